// Round 11
// baseline (113.376 us; speedup 1.0000x reference)
//
#include <hip/hip_runtime.h>
#include <stdint.h>

// ---------------- problem constants ----------------
#define B_SZ 8192
#define LOG8 2.0794415416798357f   // -log(1/8)
#define NTILE 2080                 // 64*65/2 upper-triangular 128x128 tiles

typedef __attribute__((ext_vector_type(8))) short short8;
typedef __attribute__((ext_vector_type(4))) float floatx4;

__device__ inline unsigned short f2bf(float f) {
    unsigned int u = __float_as_uint(f);
    u = (u + 0x7FFFu + ((u >> 16) & 1u)) >> 16;   // RNE
    return (unsigned short)u;
}
__device__ inline float bf2f(unsigned short s) {
    return __uint_as_float(((unsigned int)s) << 16);
}
__device__ inline float wredf(float x) {
#pragma unroll
    for (int o = 32; o; o >>= 1) x += __shfl_down(x, o);
    return x;
}
__device__ inline int wredi(int x) {
#pragma unroll
    for (int o = 32; o; o >>= 1) x += __shfl_down(x, o);
    return x;
}

// ws layout:
//  nrm      bf16[8192*128]   @ 0        (2097152 B)  -- FRAGMENT-SWIZZLED, see below
//  nlq      bf16[8192*8]     @ 2097152  (-(logp+log8), sign-flipped bf16)
//  pb       bf16[8192*8]     @ 2228224
//  aprime   f32[8192]        @ 2359296
//  slot64   u64[2080]        @ 2392064  (packed {f32 kl, u32 cnt}, atomicExch)
//  prepslot f32[256*11]      @ 2408704
//  doneCnt  u32              @ 2419968
//
// nrm fragment-swizzled layout (v5): rows grouped by 16.  Group g = row>>4
// occupies elems [g*2048, (g+1)*2048).  Within a group, element e=ks*32+q*8+j
// of row r (m=r&15) lives at offset ks*512 + q*128 + m*8 + j.  A wave's MFMA
// fragment load (lane=(q,m), 16 B) is then 64 lanes x 16 B = 1 KB fully
// contiguous.  Same bf16 values -> bit-identical fragments.

// ---------------- fused prep (256 uniform blocks x 512) ----------------
__global__ __launch_bounds__(512) void prep_all(
    const float* __restrict__ logits,
    const int* __restrict__ targets,
    const float* __restrict__ routing,
    const float* __restrict__ emb,
    unsigned short* __restrict__ nrm,
    unsigned short* __restrict__ nlq,
    unsigned short* __restrict__ pb,
    float* __restrict__ aprime,
    float* __restrict__ prepslot,
    unsigned int* __restrict__ doneCnt) {
    const int bid = blockIdx.x;
    const int lane = threadIdx.x & 63;
    const int wave = threadIdx.x >> 6;

    if (bid == 0 && threadIdx.x == 0) *doneCnt = 0u;   // ws is poisoned each iter

    // ---- embedding normalization: 32 rows per block, swizzled store ----
#pragma unroll
    for (int iter = 0; iter < 4; ++iter) {
        int row = (((iter << 8) + bid) << 3) + wave;
        const float2* e2 = (const float2*)(emb + (size_t)row * 128);
        float2 vv = e2[lane];
        float ss = vv.x * vv.x + vv.y * vv.y;
        ss = wredf(ss);
        ss = __shfl(ss, 0);
        float inv = rsqrtf(ss);
        ushort2 o;
        o.x = f2bf(vv.x * inv);
        o.y = f2bf(vv.y * inv);
        // swizzled destination: e = 2*lane (elems e, e+1 share a granule)
        const int e = lane << 1;
        const int g = row >> 4, mm = row & 15;
        const int ks = e >> 5, qq = (e >> 3) & 3, j = e & 7;
        *(ushort2*)(nrm + ((size_t)g << 11) + (ks << 9) + (qq << 7) + (mm << 3) + j) = o;
    }

    if (wave != 0) return;

    // ---- routing softmax / task / eff / ent: 32 rows, wave 0 ----
    float task = 0.f, eff = 0.f, ent = 0.f;
    float v[8] = {0.f, 0.f, 0.f, 0.f, 0.f, 0.f, 0.f, 0.f};

    if (lane < 32) {
        int row = (bid << 5) + lane;

        const float4* r4 = (const float4*)(routing + (size_t)row * 8);
        float4 va = r4[0], vb = r4[1];
        v[0] = va.x; v[1] = va.y; v[2] = va.z; v[3] = va.w;
        v[4] = vb.x; v[5] = vb.y; v[6] = vb.z; v[7] = vb.w;

        float mx = v[0];
#pragma unroll
        for (int e = 1; e < 8; ++e) mx = fmaxf(mx, v[e]);
        float ex[8], s = 0.f;
#pragma unroll
        for (int e = 0; e < 8; ++e) { ex[e] = expf(v[e] - mx); s += ex[e]; }
        float ls = logf(s);
        float inv_s = 1.f / s;

        union { unsigned short u[8]; uint4 q; } lu, pu;
        float ap = 0.f;
#pragma unroll
        for (int e = 0; e < 8; ++e) {
            unsigned short pe = f2bf(ex[e] * inv_s);
            unsigned short le = f2bf(v[e] - mx - ls + LOG8);
            pu.u[e] = pe;
            lu.u[e] = le ^ 0x8000;             // store -lq (exact sign flip)
            ap += bf2f(pe) * bf2f(le);
        }
        ((uint4*)nlq)[row] = lu.q;
        ((uint4*)pb)[row] = pu.q;
        aprime[row] = ap;

#pragma unroll
        for (int e = 0; e < 8; ++e) {
            if (v[e] < 0.1f) eff += v[e];
            ent += v[e] * logf(v[e] + 1e-8f);
        }

        const float* lg = logits + (size_t)row * 3;
        float a0 = lg[0], a1 = lg[1], a2 = lg[2];
        float mm = fmaxf(a0, fmaxf(a1, a2));
        float lse = mm + logf(expf(a0 - mm) + expf(a1 - mm) + expf(a2 - mm));
        int tg = targets[row];
        float tv = (tg == 0) ? a0 : ((tg == 1) ? a1 : a2);
        task = lse - tv;
    }

    task = wredf(task);
    eff = wredf(eff);
    ent = wredf(ent);
    float cs[8];
#pragma unroll
    for (int e = 0; e < 8; ++e) cs[e] = wredf(v[e]);

    if (lane == 0) {
        float* ps = prepslot + bid * 11;
        ps[0] = task;
        ps[1] = eff;
        ps[2] = ent;
#pragma unroll
        for (int e = 0; e < 8; ++e) ps[3 + e] = cs[e];
    }
}

// ---------------- main: symmetric fused sim-mask + KL + fused finalize ------
// 128x128 upper-tri tiles; 512 thr (8 waves 2x4); grid 2080.
// Body = R6 (best measured ~31 us): coalesced direct fragment loads from the
// swizzled nrm, no staging barriers, (512,6) -> 3 blocks/CU, VGPR~72 combined.
// v11 ending (fixes R1's failure modes): per-block ONE packed u64 atomicExch
// to a UNIQUE slot (no same-line contention), s_waitcnt vmcnt(0) (orders the
// exch at the coherence point -- NOT a threadfence/L2-writeback), one
// done-counter atomicAdd.  Last-finishing block runs the finalize in-kernel:
// slot reads via atomics (coherent), prepslot/temp plain (kernel-boundary
// visibility from prep_all).  Slot summation keeps finalize_k's exact order
// (t<256, stride 256) -> bit-identical final value.  Saves one dispatch.
__global__ __launch_bounds__(512, 6) void tile_sym(
    const unsigned short* __restrict__ nrm,
    const unsigned short* __restrict__ nlq,
    const unsigned short* __restrict__ pb,
    const float* __restrict__ aprime,
    unsigned long long* __restrict__ slot64,
    const float* __restrict__ prepslot,
    const float* __restrict__ temp,
    unsigned int* __restrict__ doneCnt,
    float* __restrict__ out) {
    __shared__ float redk[8];
    __shared__ int redc[8];
    __shared__ int isLast;
    __shared__ float fk[8];
    __shared__ int fc[8];
    __shared__ float sp[8][11];

    const int t = threadIdx.x;
    const int L = blockIdx.x;
    const int wave = t >> 6, lane = t & 63;

    // triangular decode: bi <= bj
    int bi = (int)((129.0f - sqrtf((float)(16641 - 8 * L))) * 0.5f);
    int T = bi * 64 - ((bi * (bi - 1)) >> 1);
    while (L < T) { --bi; T = bi * 64 - ((bi * (bi - 1)) >> 1); }
    while (L >= T + (64 - bi)) { T += 64 - bi; ++bi; }
    const int bj = bi + (L - T);
    const bool diag = (bi == bj);
    const int iBase = bi << 7, jBase = bj << 7;

    const int wr = wave >> 2, wc = wave & 3;   // 2 x 4 wave grid
    const int m = lane & 15, q = lane >> 4;

    // swizzled group bases: A groups (bi*8 + wr*4 + a), B groups (bj*8 + wc*2 + b)
    const unsigned short* Ag = nrm + ((size_t)((bi << 3) + (wr << 2)) << 11);
    const unsigned short* Bg = nrm + ((size_t)((bj << 3) + (wc << 1)) << 11);
    const int lo = (q << 7) + (m << 3);        // lane offset within 1 KB slab

    floatx4 simacc[4][2];
#pragma unroll
    for (int a = 0; a < 4; ++a)
#pragma unroll
        for (int b = 0; b < 2; ++b) simacc[a][b] = (floatx4){0.f, 0.f, 0.f, 0.f};

    // ---- main K loop: coalesced direct fragment loads, no barriers ----
#pragma unroll
    for (int ks = 0; ks < 4; ++ks) {
        short8 af[4], bfr[2];
#pragma unroll
        for (int a = 0; a < 4; ++a)
            af[a] = *(const short8*)(Ag + (a << 11) + (ks << 9) + lo);
#pragma unroll
        for (int b = 0; b < 2; ++b)
            bfr[b] = *(const short8*)(Bg + (b << 11) + (ks << 9) + lo);
#pragma unroll
        for (int a = 0; a < 4; ++a)
#pragma unroll
            for (int b = 0; b < 2; ++b)
                simacc[a][b] = __builtin_amdgcn_mfma_f32_16x16x32_bf16(
                    af[a], bfr[b], simacc[a][b], 0, 0, 0);
    }

    // ---- cross fragments (short live range, L2-resident) ----
    //  A: q0 = -lq_i, q1 = p_i (0 on diag), q2: k16=bf16(ap_i)(0 on diag), k17=1
    //  B: q0 = p_j,   q1 = -lq_j,           q2: k16=1, k17=bf16(ap_j)
    const short8 zero8 = (short8){0, 0, 0, 0, 0, 0, 0, 0};
    short8 crA[4], crB[2];
#pragma unroll
    for (int a = 0; a < 4; ++a) {
        int ri = iBase + (wr << 6) + (a << 4) + m;
        short8 v = zero8;
        if (q == 0) v = *(const short8*)&nlq[(size_t)ri << 3];
        else if (q == 1) { if (!diag) v = *(const short8*)&pb[(size_t)ri << 3]; }
        else if (q == 2) {
            v[1] = (short)0x3F80;
            if (!diag) v[0] = (short)f2bf(aprime[ri]);
        }
        crA[a] = v;
    }
#pragma unroll
    for (int b = 0; b < 2; ++b) {
        int cj = jBase + (wc << 5) + (b << 4) + m;
        short8 v = zero8;
        if (q == 0) v = *(const short8*)&pb[(size_t)cj << 3];
        else if (q == 1) v = *(const short8*)&nlq[(size_t)cj << 3];
        else if (q == 2) {
            v[0] = (short)0x3F80;
            v[1] = (short)f2bf(aprime[cj]);
        }
        crB[b] = v;
    }

    // epilogue: kl via one MFMA, then masked accumulate
    float klLocal = 0.f;
    int cntLocal = 0;
#pragma unroll
    for (int a = 0; a < 4; ++a) {
        const int gRow0 = iBase + (wr << 6) + (a << 4) + (q << 2);
#pragma unroll
        for (int b = 0; b < 2; ++b) {
            const int gCol = jBase + (wc << 5) + (b << 4) + m;
            floatx4 cr = __builtin_amdgcn_mfma_f32_16x16x32_bf16(
                crA[a], crB[b], (floatx4){0.f, 0.f, 0.f, 0.f}, 0, 0, 0);
            if (diag) {
#pragma unroll
                for (int r = 0; r < 4; ++r) {
                    if ((simacc[a][b][r] > 0.8f) && (gRow0 + r != gCol)) {
                        klLocal += cr[r];
                        cntLocal += 1;
                    }
                }
            } else {
#pragma unroll
                for (int r = 0; r < 4; ++r) {
                    if (simacc[a][b][r] > 0.8f) {
                        klLocal += cr[r];
                        cntLocal += 2;
                    }
                }
            }
        }
    }

    klLocal = wredf(klLocal);
    cntLocal = wredi(cntLocal);

    if (lane == 0) { redk[wave] = klLocal; redc[wave] = cntLocal; }
    __syncthreads();

    if (t == 0) {
        float k = 0.f;
        int c = 0;
#pragma unroll
        for (int w = 0; w < 8; ++w) { k += redk[w]; c += redc[w]; }
        // publish: one coherent exch to a UNIQUE slot (no contention),
        // then order it before the done-counter increment.
        unsigned long long packed =
            ((unsigned long long)__float_as_uint(k) << 32) | (unsigned int)c;
        atomicExch(&slot64[L], packed);
        asm volatile("s_waitcnt vmcnt(0)" ::: "memory");
        unsigned int prev = atomicAdd(doneCnt, 1u);
        isLast = (prev == (unsigned int)(NTILE - 1)) ? 1 : 0;
    }
    __syncthreads();
    if (isLast == 0) return;

    // ---- last-finishing block: finalize (replaces finalize_k) ----
    // slot sum in finalize_k's exact order: threads 0..255, stride 256.
    float k = 0.f;
    int c = 0;
    if (t < 256) {
        for (int i = t; i < NTILE; i += 256) {
            unsigned long long v = atomicAdd(&slot64[i], 0ull);   // coherent read
            k += __uint_as_float((unsigned int)(v >> 32));
            c += (int)(unsigned int)v;
        }
    }
    k = wredf(k);
    c = wredi(c);
    if (lane == 0) { fk[wave] = k; fc[wave] = c; }

    // prep stats: threads 0..255 own prepslot rows (256 rows exactly)
    float sv[11];
    if (t < 256) {
        const float* ps = prepslot + t * 11;
#pragma unroll
        for (int j = 0; j < 11; ++j) sv[j] = ps[j];
    } else {
#pragma unroll
        for (int j = 0; j < 11; ++j) sv[j] = 0.f;
    }
#pragma unroll
    for (int j = 0; j < 11; ++j) sv[j] = wredf(sv[j]);
    if (lane == 0) {
#pragma unroll
        for (int j = 0; j < 11; ++j) sp[wave][j] = sv[j];
    }
    __syncthreads();

    if (t == 0) {
        float K = fk[0] + fk[1] + fk[2] + fk[3];     // waves 4..7 are zero
        int C = fc[0] + fc[1] + fc[2] + fc[3];
        float st[11];
#pragma unroll
        for (int j = 0; j < 11; ++j)
            st[j] = sp[0][j] + sp[1][j] + sp[2][j] + sp[3][j];
        const float invB = 1.f / (float)B_SZ;
        float task = st[0] * invB;
        float eff = 0.05f * st[1] * invB;
        float entl = 0.01f * st[2] * invB;
        float cons = 0.1f * (C > 0 ? K / (float)C : 0.f);
        float u[8], mean = 0.f;
#pragma unroll
        for (int e = 0; e < 8; ++e) { u[e] = st[3 + e] * invB; mean += u[e]; }
        mean *= 0.125f;
        float var = 0.f;
#pragma unroll
        for (int e = 0; e < 8; ++e) { float d = u[e] - mean; var += d * d; }
        var *= (1.f / 7.f);                // unbiased (ddof=1)
        float lb = 0.1f * var * 64.f;      // * E^2
        float tt = temp[0] - 1.f;
        out[0] = task + lb + eff + cons + entl + 0.01f * tt * tt;
    }
}

// ---------------- launch ----------------
extern "C" void kernel_launch(void* const* d_in, const int* in_sizes, int n_in,
                              void* d_out, int out_size, void* d_ws, size_t ws_size,
                              hipStream_t stream) {
    const float* logits = (const float*)d_in[0];
    const int* targets = (const int*)d_in[1];
    const float* routing = (const float*)d_in[2];
    const float* emb = (const float*)d_in[3];
    const float* temp = (const float*)d_in[4];

    char* ws = (char*)d_ws;
    unsigned short* nrm = (unsigned short*)ws;
    unsigned short* nlq = (unsigned short*)(ws + 2097152);
    unsigned short* pb = (unsigned short*)(ws + 2228224);
    float* aprime = (float*)(ws + 2359296);
    unsigned long long* slot64 = (unsigned long long*)(ws + 2392064);
    float* prepslot = (float*)(ws + 2408704);
    unsigned int* doneCnt = (unsigned int*)(ws + 2419968);

    prep_all<<<256, 512, 0, stream>>>(logits, targets, routing, emb,
                                      nrm, nlq, pb, aprime, prepslot, doneCnt);
    tile_sym<<<NTILE, 512, 0, stream>>>(nrm, nlq, pb, aprime, slot64,
                                        prepslot, temp, doneCnt,
                                        (float*)d_out);
}

// Round 12
// 97.137 us; speedup vs baseline: 1.1672x; 1.1672x over previous
//
#include <hip/hip_runtime.h>
#include <stdint.h>

// ---------------- problem constants ----------------
#define B_SZ 8192
#define LOG8 2.0794415416798357f   // -log(1/8)
#define NTILE 2080                 // 64*65/2 upper-triangular 128x128 tiles

typedef __attribute__((ext_vector_type(8))) short short8;
typedef __attribute__((ext_vector_type(4))) float floatx4;

typedef __attribute__((address_space(1))) const uint4 guint4;
typedef __attribute__((address_space(3))) uint4 luint4;

// async global->LDS 16B copy: per-lane global addr, wave-uniform LDS base,
// HW scatters lane l to base + l*16.
__device__ inline void async_cp16(const uint4* g, uint4* l) {
    __builtin_amdgcn_global_load_lds((guint4*)g, (luint4*)l, 16, 0, 0);
}

__device__ inline unsigned short f2bf(float f) {
    unsigned int u = __float_as_uint(f);
    u = (u + 0x7FFFu + ((u >> 16) & 1u)) >> 16;   // RNE
    return (unsigned short)u;
}
__device__ inline float bf2f(unsigned short s) {
    return __uint_as_float(((unsigned int)s) << 16);
}
__device__ inline float wredf(float x) {
#pragma unroll
    for (int o = 32; o; o >>= 1) x += __shfl_down(x, o);
    return x;
}
__device__ inline int wredi(int x) {
#pragma unroll
    for (int o = 32; o; o >>= 1) x += __shfl_down(x, o);
    return x;
}

// ws layout:
//  nrm      bf16[8192*128]   @ 0        (2097152 B)
//  nlq      bf16[8192*8]     @ 2097152  (-(logp+log8), sign-flipped bf16)
//  pb       bf16[8192*8]     @ 2228224
//  aprime   f32[8192]        @ 2359296
//  klslot   f32[2080]        @ 2392064  (per-block, non-atomic)
//  cntslot  u32[2080]        @ 2400384
//  prepslot f32[256*11]      @ 2408704

// ---------------- fused prep (256 uniform blocks x 512) ----------------
// Every block: 32 nrm rows (8 waves x 4 iters) + 32 routing rows (wave 0,
// lanes 0..31; lanes 32..63 contribute zeros to the wave reductions).
__global__ __launch_bounds__(512) void prep_all(
    const float* __restrict__ logits,
    const int* __restrict__ targets,
    const float* __restrict__ routing,
    const float* __restrict__ emb,
    unsigned short* __restrict__ nrm,
    unsigned short* __restrict__ nlq,
    unsigned short* __restrict__ pb,
    float* __restrict__ aprime,
    float* __restrict__ prepslot) {
    const int bid = blockIdx.x;
    const int lane = threadIdx.x & 63;
    const int wave = threadIdx.x >> 6;

    // ---- embedding normalization: 32 rows per block ----
#pragma unroll
    for (int iter = 0; iter < 4; ++iter) {
        int row = (((iter << 8) + bid) << 3) + wave;
        const float2* e2 = (const float2*)(emb + (size_t)row * 128);
        float2 vv = e2[lane];
        float ss = vv.x * vv.x + vv.y * vv.y;
        ss = wredf(ss);
        ss = __shfl(ss, 0);
        float inv = rsqrtf(ss);
        ushort2 o;
        o.x = f2bf(vv.x * inv);
        o.y = f2bf(vv.y * inv);
        ((ushort2*)(nrm + (size_t)row * 128))[lane] = o;
    }

    if (wave != 0) return;

    // ---- routing softmax / task / eff / ent: 32 rows, wave 0 ----
    float task = 0.f, eff = 0.f, ent = 0.f;
    float v[8] = {0.f, 0.f, 0.f, 0.f, 0.f, 0.f, 0.f, 0.f};

    if (lane < 32) {
        int row = (bid << 5) + lane;

        const float4* r4 = (const float4*)(routing + (size_t)row * 8);
        float4 va = r4[0], vb = r4[1];
        v[0] = va.x; v[1] = va.y; v[2] = va.z; v[3] = va.w;
        v[4] = vb.x; v[5] = vb.y; v[6] = vb.z; v[7] = vb.w;

        float mx = v[0];
#pragma unroll
        for (int e = 1; e < 8; ++e) mx = fmaxf(mx, v[e]);
        float ex[8], s = 0.f;
#pragma unroll
        for (int e = 0; e < 8; ++e) { ex[e] = expf(v[e] - mx); s += ex[e]; }
        float ls = logf(s);
        float inv_s = 1.f / s;

        union { unsigned short u[8]; uint4 q; } lu, pu;
        float ap = 0.f;
#pragma unroll
        for (int e = 0; e < 8; ++e) {
            unsigned short pe = f2bf(ex[e] * inv_s);
            unsigned short le = f2bf(v[e] - mx - ls + LOG8);
            pu.u[e] = pe;
            lu.u[e] = le ^ 0x8000;             // store -lq (exact sign flip)
            ap += bf2f(pe) * bf2f(le);
        }
        ((uint4*)nlq)[row] = lu.q;
        ((uint4*)pb)[row] = pu.q;
        aprime[row] = ap;

#pragma unroll
        for (int e = 0; e < 8; ++e) {
            if (v[e] < 0.1f) eff += v[e];
            ent += v[e] * logf(v[e] + 1e-8f);
        }

        const float* lg = logits + (size_t)row * 3;
        float a0 = lg[0], a1 = lg[1], a2 = lg[2];
        float mm = fmaxf(a0, fmaxf(a1, a2));
        float lse = mm + logf(expf(a0 - mm) + expf(a1 - mm) + expf(a2 - mm));
        int tg = targets[row];
        float tv = (tg == 0) ? a0 : ((tg == 1) ? a1 : a2);
        task = lse - tv;
    }

    task = wredf(task);
    eff = wredf(eff);
    ent = wredf(ent);
    float cs[8];
#pragma unroll
    for (int e = 0; e < 8; ++e) cs[e] = wredf(v[e]);

    if (lane == 0) {
        float* ps = prepslot + bid * 11;
        ps[0] = task;
        ps[1] = eff;
        ps[2] = ent;
#pragma unroll
        for (int e = 0; e < 8; ++e) ps[3 + e] = cs[e];
    }
}

// ---------------- main: symmetric fused sim-mask + KL ----------------
// 128x128 upper-tri tiles; 512 thr (8 waves 2x4); global_load_lds staging.
// Measured champion (R3, 98.4 us total): 32 KB LDS (2 planes reused across
// k-chunks) + (512,6) -> 3 blocks/CU under an ~85-reg/wave cap.  crA/crB
// epilogue fragments are loaded AFTER the main compute (short live range)
// so the main loop fits the cap without spilling.
// LDS planes (uint4[1024] each): 0 = A-half, 1 = B-half.
// plane slot (row*8 + s) holds global granule chunk*8 + (s ^ (row&7)).
__global__ __launch_bounds__(512, 6) void tile_sym(
    const unsigned short* __restrict__ nrm,
    const unsigned short* __restrict__ nlq,
    const unsigned short* __restrict__ pb,
    const float* __restrict__ aprime,
    float* __restrict__ klslot,
    unsigned int* __restrict__ cntslot) {
    __shared__ uint4 sh[2048];   // 32 KB

    const int t = threadIdx.x;
    const int L = blockIdx.x;
    const int wave = t >> 6, lane = t & 63;

    // triangular decode: bi <= bj
    int bi = (int)((129.0f - sqrtf((float)(16641 - 8 * L))) * 0.5f);
    int T = bi * 64 - ((bi * (bi - 1)) >> 1);
    while (L < T) { --bi; T = bi * 64 - ((bi * (bi - 1)) >> 1); }
    while (L >= T + (64 - bi)) { T += 64 - bi; ++bi; }
    const int bj = bi + (L - T);
    const bool diag = (bi == bj);
    const int iBase = bi << 7, jBase = bj << 7;

    const uint4* n4 = (const uint4*)nrm;
    const int s0 = t & 7, r0 = t >> 3;            // slot t
    const int s1 = (t + 512) & 7, r1 = (t + 512) >> 3;
    const int g0 = s0 ^ (r0 & 7), g1 = s1 ^ (r1 & 7);

    // ---- issue chunk0 copies (planes 0,1 = k 0..63) ----
    async_cp16(&n4[((size_t)(iBase + r0) << 4) + g0], sh + (wave << 6));
    async_cp16(&n4[((size_t)(iBase + r1) << 4) + g1], sh + 512 + (wave << 6));
    async_cp16(&n4[((size_t)(jBase + r0) << 4) + g0], sh + 1024 + (wave << 6));
    async_cp16(&n4[((size_t)(jBase + r1) << 4) + g1], sh + 1536 + (wave << 6));

    const int wr = wave >> 2, wc = wave & 3;   // 2 x 4 wave grid
    const int m = lane & 15, q = lane >> 4;

    floatx4 simacc[4][2];
#pragma unroll
    for (int a = 0; a < 4; ++a)
#pragma unroll
        for (int b = 0; b < 2; ++b) simacc[a][b] = (floatx4){0.f, 0.f, 0.f, 0.f};

    const int m7 = m & 7;
    const int raOff = (wr << 6) << 3;              // A row base * 8
    const int rbOff = (wc << 5) << 3;              // B row base * 8

    __syncthreads();                   // drains chunk0 copies

    // ---- compute ks=0,1 from planes 0,1 (chunk0 resident) ----
#pragma unroll
    for (int ks = 0; ks < 2; ++ks) {
        const int sg = ((ks << 2) + q) ^ m7;       // gw ^ (row&7)
        short8 af[4], bfr[2];
#pragma unroll
        for (int a = 0; a < 4; ++a)
            af[a] = *(const short8*)(sh + raOff + (((a << 4) + m) << 3) + sg);
#pragma unroll
        for (int b = 0; b < 2; ++b)
            bfr[b] = *(const short8*)(sh + 1024 + rbOff + (((b << 4) + m) << 3) + sg);
#pragma unroll
        for (int a = 0; a < 4; ++a)
#pragma unroll
            for (int b = 0; b < 2; ++b)
                simacc[a][b] = __builtin_amdgcn_mfma_f32_16x16x32_bf16(
                    af[a], bfr[b], simacc[a][b], 0, 0, 0);
    }

    __syncthreads();                   // WAR: all plane reads done

    // ---- issue chunk1 copies into the SAME planes (k 64..127) ----
    async_cp16(&n4[((size_t)(iBase + r0) << 4) + 8 + g0], sh + (wave << 6));
    async_cp16(&n4[((size_t)(iBase + r1) << 4) + 8 + g1], sh + 512 + (wave << 6));
    async_cp16(&n4[((size_t)(jBase + r0) << 4) + 8 + g0], sh + 1024 + (wave << 6));
    async_cp16(&n4[((size_t)(jBase + r1) << 4) + 8 + g1], sh + 1536 + (wave << 6));

    __syncthreads();                   // drains chunk1 copies

    // ---- compute ks=2,3 from planes 0,1 ----
#pragma unroll
    for (int ks = 0; ks < 2; ++ks) {
        const int sg = ((ks << 2) + q) ^ m7;
        short8 af[4], bfr[2];
#pragma unroll
        for (int a = 0; a < 4; ++a)
            af[a] = *(const short8*)(sh + raOff + (((a << 4) + m) << 3) + sg);
#pragma unroll
        for (int b = 0; b < 2; ++b)
            bfr[b] = *(const short8*)(sh + 1024 + rbOff + (((b << 4) + m) << 3) + sg);
#pragma unroll
        for (int a = 0; a < 4; ++a)
#pragma unroll
            for (int b = 0; b < 2; ++b)
                simacc[a][b] = __builtin_amdgcn_mfma_f32_16x16x32_bf16(
                    af[a], bfr[b], simacc[a][b], 0, 0, 0);
    }

    // ---- cross fragments (loaded late: short live range, L2-resident) ----
    //  A: q0 = -lq_i, q1 = p_i (0 on diag), q2: k16=bf16(ap_i)(0 on diag), k17=1
    //  B: q0 = p_j,   q1 = -lq_j,           q2: k16=1, k17=bf16(ap_j)
    const short8 zero8 = (short8){0, 0, 0, 0, 0, 0, 0, 0};
    short8 crA[4], crB[2];
#pragma unroll
    for (int a = 0; a < 4; ++a) {
        int ri = iBase + (wr << 6) + (a << 4) + m;
        short8 v = zero8;
        if (q == 0) v = *(const short8*)&nlq[(size_t)ri << 3];
        else if (q == 1) { if (!diag) v = *(const short8*)&pb[(size_t)ri << 3]; }
        else if (q == 2) {
            v[1] = (short)0x3F80;
            if (!diag) v[0] = (short)f2bf(aprime[ri]);
        }
        crA[a] = v;
    }
#pragma unroll
    for (int b = 0; b < 2; ++b) {
        int cj = jBase + (wc << 5) + (b << 4) + m;
        short8 v = zero8;
        if (q == 0) v = *(const short8*)&pb[(size_t)cj << 3];
        else if (q == 1) v = *(const short8*)&nlq[(size_t)cj << 3];
        else if (q == 2) {
            v[0] = (short)0x3F80;
            v[1] = (short)f2bf(aprime[cj]);
        }
        crB[b] = v;
    }

    // epilogue: kl via one MFMA, then masked accumulate
    float klLocal = 0.f;
    int cntLocal = 0;
#pragma unroll
    for (int a = 0; a < 4; ++a) {
        const int gRow0 = iBase + (wr << 6) + (a << 4) + (q << 2);
#pragma unroll
        for (int b = 0; b < 2; ++b) {
            const int gCol = jBase + (wc << 5) + (b << 4) + m;
            floatx4 cr = __builtin_amdgcn_mfma_f32_16x16x32_bf16(
                crA[a], crB[b], (floatx4){0.f, 0.f, 0.f, 0.f}, 0, 0, 0);
            if (diag) {
#pragma unroll
                for (int r = 0; r < 4; ++r) {
                    if ((simacc[a][b][r] > 0.8f) && (gRow0 + r != gCol)) {
                        klLocal += cr[r];
                        cntLocal += 1;
                    }
                }
            } else {
#pragma unroll
                for (int r = 0; r < 4; ++r) {
                    if (simacc[a][b][r] > 0.8f) {
                        klLocal += cr[r];
                        cntLocal += 2;
                    }
                }
            }
        }
    }

    klLocal = wredf(klLocal);
    cntLocal = wredi(cntLocal);

    __syncthreads();
    float* redk = (float*)sh;
    int* redc = (int*)(redk + 8);
    if (lane == 0) { redk[wave] = klLocal; redc[wave] = cntLocal; }
    __syncthreads();

    if (t == 0) {
        float k = 0.f;
        int c = 0;
#pragma unroll
        for (int w = 0; w < 8; ++w) { k += redk[w]; c += redc[w]; }
        klslot[L] = k;                     // unique slot: no atomic
        cntslot[L] = (unsigned int)c;
    }
}

// ---------------- finalize (1 block x 256) ----------------
__global__ void finalize_k(const float* __restrict__ klslot,
                           const unsigned int* __restrict__ cntslot,
                           const float* __restrict__ prepslot,
                           const float* __restrict__ temp,
                           float* __restrict__ out) {
    __shared__ float sk[4];
    __shared__ int sc[4];
    __shared__ float sp[4][11];
    const int t = threadIdx.x, lane = t & 63, wave = t >> 6;

    float k = 0.f;
    int c = 0;
    for (int i = t; i < NTILE; i += 256) { k += klslot[i]; c += (int)cntslot[i]; }
    k = wredf(k);
    c = wredi(c);
    if (lane == 0) { sk[wave] = k; sc[wave] = c; }

    // prep stats: thread t owns prepslot row t (256 rows exactly)
    float sv[11];
    const float* ps = prepslot + t * 11;
#pragma unroll
    for (int j = 0; j < 11; ++j) sv[j] = ps[j];
#pragma unroll
    for (int j = 0; j < 11; ++j) sv[j] = wredf(sv[j]);
    if (lane == 0) {
#pragma unroll
        for (int j = 0; j < 11; ++j) sp[wave][j] = sv[j];
    }
    __syncthreads();

    if (t == 0) {
        float K = sk[0] + sk[1] + sk[2] + sk[3];
        int C = sc[0] + sc[1] + sc[2] + sc[3];
        float st[11];
#pragma unroll
        for (int j = 0; j < 11; ++j)
            st[j] = sp[0][j] + sp[1][j] + sp[2][j] + sp[3][j];
        const float invB = 1.f / (float)B_SZ;
        float task = st[0] * invB;
        float eff = 0.05f * st[1] * invB;
        float entl = 0.01f * st[2] * invB;
        float cons = 0.1f * (C > 0 ? K / (float)C : 0.f);
        float u[8], mean = 0.f;
#pragma unroll
        for (int e = 0; e < 8; ++e) { u[e] = st[3 + e] * invB; mean += u[e]; }
        mean *= 0.125f;
        float var = 0.f;
#pragma unroll
        for (int e = 0; e < 8; ++e) { float d = u[e] - mean; var += d * d; }
        var *= (1.f / 7.f);                // unbiased (ddof=1)
        float lb = 0.1f * var * 64.f;      // * E^2
        float tt = temp[0] - 1.f;
        out[0] = task + lb + eff + cons + entl + 0.01f * tt * tt;
    }
}

// ---------------- launch ----------------
extern "C" void kernel_launch(void* const* d_in, const int* in_sizes, int n_in,
                              void* d_out, int out_size, void* d_ws, size_t ws_size,
                              hipStream_t stream) {
    const float* logits = (const float*)d_in[0];
    const int* targets = (const int*)d_in[1];
    const float* routing = (const float*)d_in[2];
    const float* emb = (const float*)d_in[3];
    const float* temp = (const float*)d_in[4];

    char* ws = (char*)d_ws;
    unsigned short* nrm = (unsigned short*)ws;
    unsigned short* nlq = (unsigned short*)(ws + 2097152);
    unsigned short* pb = (unsigned short*)(ws + 2228224);
    float* aprime = (float*)(ws + 2359296);
    float* klslot = (float*)(ws + 2392064);
    unsigned int* cntslot = (unsigned int*)(ws + 2400384);
    float* prepslot = (float*)(ws + 2408704);

    prep_all<<<256, 512, 0, stream>>>(logits, targets, routing, emb,
                                      nrm, nlq, pb, aprime, prepslot);
    tile_sym<<<NTILE, 512, 0, stream>>>(nrm, nlq, pb, aprime, klslot, cntslot);
    finalize_k<<<1, 256, 0, stream>>>(klslot, cntslot, prepslot, temp,
                                      (float*)d_out);
}